// Round 12
// baseline (137.251 us; speedup 1.0000x reference)
//
#include <hip/hip_runtime.h>
#include <hip/hip_bf16.h>

#define DEV __device__ __forceinline__

typedef __attribute__((ext_vector_type(8)))  __bf16    bf16x8;
typedef __attribute__((ext_vector_type(4)))  int       int4v;
typedef __attribute__((ext_vector_type(2)))  unsigned  uint2v;
typedef __attribute__((ext_vector_type(16))) float     vfloat16;

#if __has_builtin(__builtin_amdgcn_permlane32_swap)
#define HAVE_PLSWAP 1
#endif

// pack two fp32 -> one dword of two bf16 (round-nearest-ties-up): 2 adds + 1 perm
DEV int pkbf(float a, float b) {
    unsigned ua = __builtin_bit_cast(unsigned, a) + 0x8000u;
    unsigned ub = __builtin_bit_cast(unsigned, b) + 0x8000u;
    return (int)__builtin_amdgcn_perm(ua, ub, 0x03020706u);
}

DEV bf16x8 i4_to_frag(int4v v) { return __builtin_bit_cast(bf16x8, v); }

DEV vfloat16 mfma32(bf16x8 a, bf16x8 b, vfloat16 c) {
    return __builtin_amdgcn_mfma_f32_32x32x16_bf16(a, b, c, 0, 0, 0);
}

// ---- C-layout 8-reg group -> B-frag (K=16), relu folded ----
// C layout: col=lane&31, row=(reg&3)+8*(reg>>2)+4*h   (h = lane>=32)
// B layout: n=lane&31,  k=(lane>>5)*8+j
DEV bf16x8 xposeB(float c0, float c1, float c2, float c3,
                  float c4, float c5, float c6, float c7, bool h) {
    int R0 = pkbf(fmaxf(c0, 0.f), fmaxf(c1, 0.f));   // rows (0,1)+4h
    int R1 = pkbf(fmaxf(c2, 0.f), fmaxf(c3, 0.f));   // rows (2,3)+4h
    int R2 = pkbf(fmaxf(c4, 0.f), fmaxf(c5, 0.f));   // rows (8,9)+4h
    int R3 = pkbf(fmaxf(c6, 0.f), fmaxf(c7, 0.f));   // rows (10,11)+4h
#ifdef HAVE_PLSWAP
    uint2v p0 = __builtin_amdgcn_permlane32_swap((unsigned)R0, (unsigned)R2, false, false);
    uint2v p1 = __builtin_amdgcn_permlane32_swap((unsigned)R1, (unsigned)R3, false, false);
    int4v v;
    v.x = (int)p0.x; v.y = (int)p1.x; v.z = (int)p0.y; v.w = (int)p1.y;
#else
    int S0 = h ? R0 : R2;
    int S1 = h ? R1 : R3;
    int Y0 = __shfl_xor(S0, 32, 64);
    int Y1 = __shfl_xor(S1, 32, 64);
    int4v v;
    v.x = h ? Y0 : R0;
    v.y = h ? Y1 : R1;
    v.z = h ? R2 : Y0;
    v.w = h ? R3 : Y1;
#endif
    return i4_to_frag(v);
}

// A-frag: A[m][k_global], m=lane&31, k_global = koff + 8*h + j.
// W row-major (K, ld): W[k][m].  Rows m>=Mact zero; k>=K zero.
// If bias != null, the k_global == K slot carries bias[m].
DEV bf16x8 make_afrag(const float* __restrict__ W, const float* __restrict__ bias,
                      int ld, int Mact, int K, int koff, int lane) {
    int m = lane & 31;
    int h = lane >> 5;
    int d[4];
#pragma unroll
    for (int i = 0; i < 4; ++i) {
        int k0 = koff + h * 8 + 2 * i;
        int k1 = k0 + 1;
        float w0 = 0.f, w1 = 0.f;
        if (m < Mact) {
            if (k0 < K) w0 = W[k0 * ld + m];
            else if (bias && k0 == K) w0 = bias[m];
            if (k1 < K) w1 = W[k1 * ld + m];
            else if (bias && k1 == K) w1 = bias[m];
        }
        d[i] = pkbf(w0, w1);
    }
    int4v v; v.x = d[0]; v.y = d[1]; v.z = d[2]; v.w = d[3];
    return i4_to_frag(v);
}

// bias vector in C layout (all 32 rows)
DEV vfloat16 bvec32(const float* __restrict__ b, int lane) {
    int h = lane >> 5;
    vfloat16 v;
#pragma unroll
    for (int reg = 0; reg < 16; ++reg)
        v[reg] = b[(reg & 3) + 8 * (reg >> 2) + 4 * h];
    return v;
}
// bias vector, rows 0..15 only (regs 0..7), upper 8 zero
DEV vfloat16 bvec16(const float* __restrict__ b, int lane) {
    int h = lane >> 5;
    vfloat16 v;
#pragma unroll
    for (int reg = 0; reg < 16; ++reg)
        v[reg] = (reg < 8) ? b[(reg & 3) + 8 * (reg >> 2) + 4 * h] : 0.f;
    return v;
}

DEV vfloat16 zero16() {
    vfloat16 z;
#pragma unroll
    for (int i = 0; i < 16; ++i) z[i] = 0.f;
    return z;
}

// B1 frag from pre-packed LDS dwords: x at k=0..3, 1.0 at k=4 (bias slot).
// h-lanes map to k=8..15 where A1 is zero -> no masking needed.
DEV bf16x8 b1_from(int2 d) {
    int4v v;
    v.x = d.x;
    v.y = d.y;
    v.z = 0x00003f80;          // bf16(1.0) at k=4
    v.w = 0;
    return i4_to_frag(v);
}

struct Frags {
    bf16x8 A1, A2lo, A2hi, A3lo, A3hi;
    vfloat16 b2, b3;   // L2/L3 biases as MFMA C-operand inits (L1 bias rides k=4)
};

DEV void load_frags(Frags& F,
                    const float* __restrict__ W1, const float* __restrict__ b1,
                    const float* __restrict__ W2, const float* __restrict__ b2,
                    const float* __restrict__ W3, const float* __restrict__ b3,
                    int lane) {
    F.A1   = make_afrag(W1, b1,      32, 32, 4,  0,  lane);
    F.A2lo = make_afrag(W2, nullptr, 32, 32, 32, 0,  lane);
    F.A2hi = make_afrag(W2, nullptr, 32, 32, 32, 16, lane);
    F.A3lo = make_afrag(W3, nullptr, 16, 16, 32, 0,  lane);
    F.A3hi = make_afrag(W3, nullptr, 16, 16, 32, 16, lane);
    F.b2 = bvec32(b2, lane);
    F.b3 = bvec16(b3, lane);
}

// single chain (epilogue): L1..L3, returns pre-relu C3 (regs 0..7 valid)
DEV vfloat16 run_mlp3(bf16x8 B1, const Frags& F, bool h) {
    vfloat16 C1 = mfma32(F.A1, B1, zero16());
    bf16x8 Blo = xposeB(C1[0], C1[1], C1[2], C1[3], C1[4], C1[5], C1[6], C1[7], h);
    bf16x8 Bhi = xposeB(C1[8], C1[9], C1[10], C1[11], C1[12], C1[13], C1[14], C1[15], h);
    vfloat16 C2 = mfma32(F.A2lo, Blo, F.b2);
    C2 = mfma32(F.A2hi, Bhi, C2);
    Blo = xposeB(C2[0], C2[1], C2[2], C2[3], C2[4], C2[5], C2[6], C2[7], h);
    Bhi = xposeB(C2[8], C2[9], C2[10], C2[11], C2[12], C2[13], C2[14], C2[15], h);
    vfloat16 C3 = mfma32(F.A3lo, Blo, F.b3);
    C3 = mfma32(F.A3hi, Bhi, C3);
    return C3;
}

// LDS x-stage: pre-packed bf16, [agent][row] int2, agent stride 66 dwords
#define XSTRIDE 66

// ==== Round-12 structure: WAVE-INDEPENDENT, BARRIER-FREE ====
// Each wave owns 32 batch rows x all 32 agents: no cross-wave reduce, no
// __syncthreads anywhere, every wave runs its own epilogue (R6-R11: 4-way
// agent split left the main loop at only 4 pair-iters vs ~4k cyc of
// prologue+wave0-epilogue overhead -> 85% stall).  Block = 4 independent
// waves = 128 rows; grid 512 blocks.
__global__ __launch_bounds__(256)
void dqn_kernel(const float* __restrict__ x, const int* __restrict__ selp,
                const float* __restrict__ oW1, const float* __restrict__ ob1,
                const float* __restrict__ oW2, const float* __restrict__ ob2,
                const float* __restrict__ oW3, const float* __restrict__ ob3,
                const float* __restrict__ sW1, const float* __restrict__ sb1,
                const float* __restrict__ sW2, const float* __restrict__ sb2,
                const float* __restrict__ sW3, const float* __restrict__ sb3,
                const float* __restrict__ gW1, const float* __restrict__ gb1,
                const float* __restrict__ gW2, const float* __restrict__ gb2,
                float* __restrict__ out)
{
    __shared__ int   lds_xb[4][32 * XSTRIDE];  // 33.8 KB: per-wave packed x
    __shared__ float lds_act[4][32];           // fp32 action feature per row

    const int tid  = threadIdx.x;
    const int lane = tid & 63;
    const int wave = tid >> 6;
    const bool h = lane >= 32;
    const int c = lane & 31;
    const int sel = *selp;
    const int base0 = blockIdx.x * 128 + wave * 32;   // this wave's 32 rows

    // ---- stage own 32x32 tile: coalesced fp32 float4 -> bf16 -> LDS ----
    // (within-wave write->read ordering handled by compiler lgkmcnt; no
    //  cross-wave LDS sharing -> no barrier)
    {
        const float* xblk = x + (size_t)base0 * 128;
#pragma unroll
        for (int k = 0; k < 16; ++k) {
            int f = lane + 64 * k;            // float4 cell: row = f>>5, agent = f&31
            int row = f >> 5;
            int ag  = f & 31;
            float4 v = *(const float4*)(xblk + (size_t)f * 4);
            if (ag == sel) lds_act[wave][row] = v.w;   // fp32 action (exactness!)
            int2 d;
            d.x = pkbf(v.x, v.y);
            d.y = pkbf(v.z, v.w);
            *(int2*)&lds_xb[wave][ag * XSTRIDE + row * 2] = d;
        }
    }

    // "other"-MLP weight fragments (overlap staging latency; L2-hot after blk 0)
    Frags Fo;
    load_frags(Fo, oW1, ob1, oW2, ob2, oW3, ob3, lane);

    // ---- main loop: ALL 32 agents, two chains interleaved ----
    float sum[8] = {0.f, 0.f, 0.f, 0.f, 0.f, 0.f, 0.f, 0.f};
    const int* xb = &lds_xb[wave][c * 2];

    for (int i = 0; i < 32; i += 2) {
        int2 da = *(const int2*)(xb + i * XSTRIDE);
        int2 db = *(const int2*)(xb + (i + 1) * XSTRIDE);

        vfloat16 C1a = mfma32(Fo.A1, b1_from(da), zero16());
        vfloat16 C1b = mfma32(Fo.A1, b1_from(db), zero16());

        bf16x8 Bal = xposeB(C1a[0], C1a[1], C1a[2], C1a[3], C1a[4], C1a[5], C1a[6], C1a[7], h);
        bf16x8 Bbl = xposeB(C1b[0], C1b[1], C1b[2], C1b[3], C1b[4], C1b[5], C1b[6], C1b[7], h);
        bf16x8 Bah = xposeB(C1a[8], C1a[9], C1a[10], C1a[11], C1a[12], C1a[13], C1a[14], C1a[15], h);
        bf16x8 Bbh = xposeB(C1b[8], C1b[9], C1b[10], C1b[11], C1b[12], C1b[13], C1b[14], C1b[15], h);

        vfloat16 C2a = mfma32(Fo.A2lo, Bal, Fo.b2);
        vfloat16 C2b = mfma32(Fo.A2lo, Bbl, Fo.b2);
        C2a = mfma32(Fo.A2hi, Bah, C2a);
        C2b = mfma32(Fo.A2hi, Bbh, C2b);

        Bal = xposeB(C2a[0], C2a[1], C2a[2], C2a[3], C2a[4], C2a[5], C2a[6], C2a[7], h);
        Bbl = xposeB(C2b[0], C2b[1], C2b[2], C2b[3], C2b[4], C2b[5], C2b[6], C2b[7], h);
        Bah = xposeB(C2a[8], C2a[9], C2a[10], C2a[11], C2a[12], C2a[13], C2a[14], C2a[15], h);
        Bbh = xposeB(C2b[8], C2b[9], C2b[10], C2b[11], C2b[12], C2b[13], C2b[14], C2b[15], h);

        vfloat16 C3a = mfma32(Fo.A3lo, Bal, Fo.b3);
        vfloat16 C3b = mfma32(Fo.A3lo, Bbl, Fo.b3);
        C3a = mfma32(Fo.A3hi, Bah, C3a);
        C3b = mfma32(Fo.A3hi, Bbh, C3b);

        if (i != sel) {
#pragma unroll
            for (int j = 0; j < 8; ++j) sum[j] += fmaxf(C3a[j], 0.f);
        }
        if (i + 1 != sel) {
#pragma unroll
            for (int j = 0; j < 8; ++j) sum[j] += fmaxf(C3b[j], 0.f);
        }
    }

    // ---- epilogue (every wave, for its own 32 rows) ----
    Frags Fs;
    load_frags(Fs, sW1, sb1, sW2, sb2, sW3, sb3, lane);
    int2 dsx = *(const int2*)&lds_xb[wave][sel * XSTRIDE + c * 2];
    vfloat16 C3s = run_mlp3(b1_from(dsx), Fs, h);

    // gate layer 1: concat([sel_out, sum_other]) @ gW1 + gb1, relu
    bf16x8 Ag_lo = make_afrag(gW1, nullptr, 32, 32, 32, 0,  lane);
    bf16x8 Ag_hi = make_afrag(gW1, nullptr, 32, 32, 32, 16, lane);
    vfloat16 gb1v = bvec32(gb1, lane);
    bf16x8 Bg_lo = xposeB(C3s[0], C3s[1], C3s[2], C3s[3],
                          C3s[4], C3s[5], C3s[6], C3s[7], h);   // relu folded
    bf16x8 Bg_hi = xposeB(sum[0], sum[1], sum[2], sum[3],
                          sum[4], sum[5], sum[6], sum[7], h);   // sums >= 0
    vfloat16 G = mfma32(Ag_lo, Bg_lo, gb1v);
    G = mfma32(Ag_hi, Bg_hi, G);
#pragma unroll
    for (int i = 0; i < 16; ++i) G[i] = fmaxf(G[i], 0.f);

    // gate layer 2 (32 -> 2) in fp32 VALU + cross-half reduce
    float q0 = 0.f, q1 = 0.f;
#pragma unroll
    for (int reg = 0; reg < 16; ++reg) {
        int row = (reg & 3) + 8 * (reg >> 2) + (h ? 4 : 0);
        q0 += G[reg] * gW2[row * 2 + 0];
        q1 += G[reg] * gW2[row * 2 + 1];
    }
    q0 += __shfl_xor(q0, 32, 64);
    q1 += __shfl_xor(q1, 32, 64);
    q0 += gb2[0];
    q1 += gb2[1];

    if (!h) {
        float f3 = lds_act[wave][c];      // exact fp32 action feature
        int act = (int)f3;
        act = act < 0 ? 0 : (act > 1 ? 1 : act);
        out[base0 + c] = act ? q1 : q0;
    }
}

extern "C" void kernel_launch(void* const* d_in, const int* in_sizes, int n_in,
                              void* d_out, int out_size, void* d_ws, size_t ws_size,
                              hipStream_t stream) {
    const float* x   = (const float*)d_in[0];
    const int*   sel = (const int*)d_in[1];
    const float* oW1 = (const float*)d_in[2];
    const float* ob1 = (const float*)d_in[3];
    const float* oW2 = (const float*)d_in[4];
    const float* ob2 = (const float*)d_in[5];
    const float* oW3 = (const float*)d_in[6];
    const float* ob3 = (const float*)d_in[7];
    const float* sW1 = (const float*)d_in[8];
    const float* sb1 = (const float*)d_in[9];
    const float* sW2 = (const float*)d_in[10];
    const float* sb2 = (const float*)d_in[11];
    const float* sW3 = (const float*)d_in[12];
    const float* sb3 = (const float*)d_in[13];
    const float* gW1 = (const float*)d_in[14];
    const float* gb1 = (const float*)d_in[15];
    const float* gW2 = (const float*)d_in[16];
    const float* gb2 = (const float*)d_in[17];
    float* out = (float*)d_out;

    const int B = in_sizes[0] / 128;       // 65536
    const int blocks = B / 128;            // 512: 128 rows/block, 32 rows/wave
    dqn_kernel<<<blocks, 256, 0, stream>>>(x, sel,
                                           oW1, ob1, oW2, ob2, oW3, ob3,
                                           sW1, sb1, sW2, sb2, sW3, sb3,
                                           gW1, gb1, gW2, gb2, out);
}